// Round 10
// baseline (263.415 us; speedup 1.0000x reference)
//
#include <hip/hip_runtime.h>
#include <hip/hip_bf16.h>

#define D_ 128
#define E_ 100
#define K_ 4
#define C_ 400
#define TILE 64
#define NB 256
#define NCOPY 16

// ws layout (f32 slots):
//   [0, 51200)    sums f32[C][D]     (written by k_reduce / fallback atomics)
//   [51200,51600) countsF f32[C]
//   [51600]       loss f32
//   [51712, +NCOPY*51200)  psum copies
//   [OFF_PCNT, +NCOPY*400) pcnt copies
#define OFF_COUNTS (C_ * D_)
#define OFF_LOSS   (OFF_COUNTS + C_)
#define OFF_PSUM   (OFF_LOSS + 112)
#define OFF_PCNT   (OFF_PSUM + NCOPY * C_ * D_)
#define WS_PRIMARY ((size_t)(OFF_PCNT + NCOPY * C_) * 4)

template <int CTRL>
__device__ __forceinline__ float dpp_add(float x) {
  int y = __builtin_amdgcn_update_dpp(0, __builtin_bit_cast(int, x),
                                      CTRL, 0xF, 0xF, true);
  return x + __builtin_bit_cast(float, y);
}

// Fused streaming assign + segment-sum.
// Per 64-atom tile: phase2 = 16 waves x 4 atoms (16 lanes/atom) argmin +
// hq write + code -> LDS; barrier; phase3 = wave w owns codes [25w,25w+25),
// ballot-scan the tile's codes, re-read matched rows from global (L2-hot)
// as full-wave float2, accumulate into 25 named float2 regs (uniform switch).
__global__ __launch_bounds__(1024) void k_fused(
    const float* __restrict__ h, const int* __restrict__ ei,
    const float* __restrict__ cb, float* __restrict__ hq,
    float* __restrict__ at, float* __restrict__ psum,
    float* __restrict__ pcnt, float* __restrict__ lossp,
    int N, int ntiles, int ncopy) {
  __shared__ int codes[TILE];
  __shared__ unsigned hist[C_];
  __shared__ float bl;
  const int tid = threadIdx.x;
  const int w = tid >> 6;
  const int lane = tid & 63;
  const int g = lane >> 4;
  const int t = lane & 15;
  const int cbase = w * 25;
  for (int i = tid; i < C_; i += 1024) hist[i] = 0u;
  if (tid == 0) bl = 0.f;

  const float4* h4 = (const float4*)h;
  const float4* cb4 = (const float4*)cb;
  float4* hq4 = (float4*)hq;

  float lossl = 0.f;
  float2 A0={0,0},A1={0,0},A2={0,0},A3={0,0},A4={0,0},A5={0,0},A6={0,0},
         A7={0,0},A8={0,0},A9={0,0},A10={0,0},A11={0,0},A12={0,0},A13={0,0},
         A14={0,0},A15={0,0},A16={0,0},A17={0,0},A18={0,0},A19={0,0},
         A20={0,0},A21={0,0},A22={0,0},A23={0,0},A24={0,0};

  const int blk0 = blockIdx.x * (ntiles * TILE);
  __syncthreads();

  for (int tile = 0; tile < ntiles; ++tile) {
    const int a0 = blk0 + tile * TILE;
    const int a = a0 + w * 4 + g;
    const bool ok = a < N;
    int code = -1;
    if (ok) {
      const int e = ei[a];
      float4 hA = h4[(size_t)a * 32 + t * 2];
      float4 hB = h4[(size_t)a * 32 + t * 2 + 1];
      const size_t cb0 = (size_t)e * (K_ * 32);
      float4 cA[4], cB[4];
      float p[4];
#pragma unroll
      for (int j = 0; j < 4; ++j) {
        cA[j] = cb4[cb0 + j * 32 + t * 2];
        cB[j] = cb4[cb0 + j * 32 + t * 2 + 1];
        float d0 = hA.x - cA[j].x, d1 = hA.y - cA[j].y;
        float d2 = hA.z - cA[j].z, d3 = hA.w - cA[j].w;
        float d4 = hB.x - cB[j].x, d5 = hB.y - cB[j].y;
        float d6 = hB.z - cB[j].z, d7 = hB.w - cB[j].w;
        p[j] = ((d0*d0 + d1*d1) + (d2*d2 + d3*d3)) +
               ((d4*d4 + d5*d5) + (d6*d6 + d7*d7));
      }
#pragma unroll
      for (int j = 0; j < 4; ++j) {
        p[j] = dpp_add<0xB1>(p[j]);    // quad_perm xor1
        p[j] = dpp_add<0x4E>(p[j]);    // quad_perm xor2
        p[j] = dpp_add<0x141>(p[j]);   // row_half_mirror
        p[j] = dpp_add<0x140>(p[j]);   // row_mirror -> 16-lane sum
      }
      int best = 0; float bp = p[0];
      if (p[1] < bp) { bp = p[1]; best = 1; }
      if (p[2] < bp) { bp = p[2]; best = 2; }
      if (p[3] < bp) { bp = p[3]; best = 3; }
      float4 qA = cA[0], qB = cB[0];
      if (best == 1) { qA = cA[1]; qB = cB[1]; }
      if (best == 2) { qA = cA[2]; qB = cB[2]; }
      if (best == 3) { qA = cA[3]; qB = cB[3]; }
      hq4[(size_t)a * 32 + t * 2]     = qA;
      hq4[(size_t)a * 32 + t * 2 + 1] = qB;
      code = e * K_ + best;
      if (t == 0) {
        at[a] = (float)code;
        lossl += bp;
        atomicAdd(&hist[code], 1u);
      }
    }
    if (t == 0) codes[w * 4 + g] = code;
    __syncthreads();

    // phase 3: lane <-> tile-atom (TILE == wave width)
    int myc = codes[lane];
    int cl = myc - cbase;
    unsigned long long m = __ballot(myc >= 0 && cl >= 0 && cl < 25);
    while (m) {
      int s = __ffsll((unsigned long long)m) - 1;
      m &= m - 1;
      int cc = __shfl(cl, s, 64);    // wave-uniform
      float2 v = *(const float2*)(h + (size_t)(a0 + s) * D_ + lane * 2);
      switch (cc) {
        case 0:  A0.x+=v.x;  A0.y+=v.y;  break;
        case 1:  A1.x+=v.x;  A1.y+=v.y;  break;
        case 2:  A2.x+=v.x;  A2.y+=v.y;  break;
        case 3:  A3.x+=v.x;  A3.y+=v.y;  break;
        case 4:  A4.x+=v.x;  A4.y+=v.y;  break;
        case 5:  A5.x+=v.x;  A5.y+=v.y;  break;
        case 6:  A6.x+=v.x;  A6.y+=v.y;  break;
        case 7:  A7.x+=v.x;  A7.y+=v.y;  break;
        case 8:  A8.x+=v.x;  A8.y+=v.y;  break;
        case 9:  A9.x+=v.x;  A9.y+=v.y;  break;
        case 10: A10.x+=v.x; A10.y+=v.y; break;
        case 11: A11.x+=v.x; A11.y+=v.y; break;
        case 12: A12.x+=v.x; A12.y+=v.y; break;
        case 13: A13.x+=v.x; A13.y+=v.y; break;
        case 14: A14.x+=v.x; A14.y+=v.y; break;
        case 15: A15.x+=v.x; A15.y+=v.y; break;
        case 16: A16.x+=v.x; A16.y+=v.y; break;
        case 17: A17.x+=v.x; A17.y+=v.y; break;
        case 18: A18.x+=v.x; A18.y+=v.y; break;
        case 19: A19.x+=v.x; A19.y+=v.y; break;
        case 20: A20.x+=v.x; A20.y+=v.y; break;
        case 21: A21.x+=v.x; A21.y+=v.y; break;
        case 22: A22.x+=v.x; A22.y+=v.y; break;
        case 23: A23.x+=v.x; A23.y+=v.y; break;
        case 24: A24.x+=v.x; A24.y+=v.y; break;
        default: break;
      }
    }
    __syncthreads();
  }

  // flush: per-wave 25 owned codes -> psum copy (16-way addr contention)
  float* myps = psum + (size_t)(blockIdx.x % ncopy) * (C_ * D_);
#define FL(i) { unsafeAtomicAdd(&myps[(size_t)(cbase+i)*D_ + lane*2],   A##i.x); \
                unsafeAtomicAdd(&myps[(size_t)(cbase+i)*D_ + lane*2+1], A##i.y); }
  FL(0) FL(1) FL(2) FL(3) FL(4) FL(5) FL(6) FL(7) FL(8) FL(9) FL(10) FL(11)
  FL(12) FL(13) FL(14) FL(15) FL(16) FL(17) FL(18) FL(19) FL(20) FL(21)
  FL(22) FL(23) FL(24)
#undef FL
  float* mypc = pcnt + (size_t)(blockIdx.x % ncopy) * C_;
  for (int i = tid; i < C_; i += 1024) {
    unsigned v = hist[i];
    if (v) unsafeAtomicAdd(&mypc[i], (float)v);
  }
  if (t == 0 && lossl != 0.f) atomicAdd(&bl, lossl);
  __syncthreads();
  if (tid == 0) unsafeAtomicAdd(lossp, bl);
}

// Reduce the NCOPY partial copies -> sums, countsF.
__global__ __launch_bounds__(256) void k_reduce(
    const float* __restrict__ psum, const float* __restrict__ pcnt,
    float* __restrict__ sums, float* __restrict__ countsF) {
  int idx = blockIdx.x * 256 + threadIdx.x;
  if (idx < C_ * D_) {
    float s = 0.f;
#pragma unroll
    for (int c = 0; c < NCOPY; ++c) s += psum[(size_t)c * (C_ * D_) + idx];
    sums[idx] = s;
  }
  if (idx < C_) {
    float s = 0.f;
#pragma unroll
    for (int c = 0; c < NCOPY; ++c) s += pcnt[(size_t)c * C_ + idx];
    countsF[idx] = s;
  }
}

// EMA finalize + loss scalar.
__global__ __launch_bounds__(256) void k_final(
    const float* __restrict__ cb, const float* __restrict__ ecnt,
    const float* __restrict__ esum, const float* __restrict__ ws,
    float* __restrict__ out, int N) {
  const float* sums = ws;
  const float* countsF = ws + OFF_COUNTS;
  int idx = blockIdx.x * 256 + threadIdx.x;
  const size_t base = (size_t)N * D_ + N + 1;
  if (idx < C_ * D_) {
    int c = idx >> 7;
    int e4 = (c >> 2) << 2;
    bool present = (countsF[e4] + countsF[e4 + 1] + countsF[e4 + 2] + countsF[e4 + 3]) > 0.f;
    float es = esum[idx];
    float s  = sums[idx];
    float ns = present ? 0.99f * es + 0.01f * s : es;
    float ec = ecnt[c];
    float nc = present ? 0.99f * ec + 0.01f * countsF[c] : ec;
    float ncbv = present ? ns / fmaxf(nc, 1e-5f) : cb[idx];
    out[base + idx] = ncbv;
    if ((idx & 127) == 0) out[base + C_ * D_ + c] = nc;
    out[base + C_ * D_ + C_ + idx] = ns;
  }
  if (idx == 0) {
    float loss = ws[OFF_LOSS];
    out[(size_t)N * D_ + N] = 0.25f * loss / ((float)N * (float)D_);
  }
}

extern "C" void kernel_launch(void* const* d_in, const int* in_sizes, int n_in,
                              void* d_out, int out_size, void* d_ws, size_t ws_size,
                              hipStream_t stream) {
  // Identify inputs by size (robust to input-order changes).
  const float* h = nullptr; const int* ei = nullptr;
  const float* cb = nullptr; const float* ecnt = nullptr; const float* esum = nullptr;
  long hsz = -1; int hidx = -1;
  for (int i = 0; i < n_in; ++i)
    if ((long)in_sizes[i] > hsz) { hsz = in_sizes[i]; hidx = i; }
  h = (const float*)d_in[hidx];
  const int N = (int)(hsz / D_);
  for (int i = 0; i < n_in; ++i) {
    if (i == hidx) continue;
    const int s = in_sizes[i];
    if (s == N) ei = (const int*)d_in[i];
    else if (s == C_) ecnt = (const float*)d_in[i];
    else if (s == C_ * D_) { if (!cb) cb = (const float*)d_in[i]; else esum = (const float*)d_in[i]; }
  }

  float* out = (float*)d_out;
  float* hq  = out;
  float* at  = out + (size_t)N * D_;

  float* ws = (float*)d_ws;
  float* sums    = ws;
  float* countsF = ws + OFF_COUNTS;
  float* lossp   = ws + OFF_LOSS;
  float* psum    = ws + OFF_PSUM;
  float* pcnt    = ws + OFF_PCNT;

  const int perblk = (((N + NB - 1) / NB) + TILE - 1) / TILE * TILE;
  const int ntiles = perblk / TILE;
  const bool primary = ws_size >= WS_PRIMARY;

  if (primary) {
    // zero loss + psum + pcnt (sums/countsF fully written by k_reduce)
    hipMemsetAsync(ws + OFF_LOSS, 0,
                   (size_t)(OFF_PCNT + NCOPY * C_ - OFF_LOSS) * 4, stream);
    k_fused<<<NB, 1024, 0, stream>>>(h, ei, cb, hq, at, psum, pcnt, lossp,
                                     N, ntiles, NCOPY);
    k_reduce<<<(C_ * D_ + 255) / 256, 256, 0, stream>>>(psum, pcnt, sums, countsF);
  } else {
    // fallback: accumulate straight into sums/countsF (1 copy)
    hipMemsetAsync(d_ws, 0, (size_t)(OFF_LOSS + 1) * 4, stream);
    k_fused<<<NB, 1024, 0, stream>>>(h, ei, cb, hq, at, sums, countsF, lossp,
                                     N, ntiles, 1);
  }
  k_final<<<(C_ * D_ + 255) / 256, 256, 0, stream>>>(cb, ecnt, esum, ws, out, N);
}

// Round 11
// 115.554 us; speedup vs baseline: 2.2796x; 2.2796x over previous
//
#include <hip/hip_runtime.h>
#include <hip/hip_bf16.h>

#define D_ 128
#define E_ 100
#define K_ 4
#define C_ 400
#define NCHUNK 128     // atom chunks in k_sums3 (x2 dim-halves = 256 blocks)
#define SCALE 65536.0f
#define INV_SCALE (1.0f / 65536.0f)

// ws layout (f32/i32 slots):
//   [0, 51200)        sums f32[C][D]
//   [51200, 51600)    countsF f32[C]
//   [51600]           loss f32
//   [51712, +256*25600)  psumI: per-block [400][64] s32 partials
//   [OFF_PCNT, +128*400) pcntI: per-chunk s32 counts
#define OFF_COUNTS 51200
#define OFF_LOSS   51600
#define OFF_PSUM   51712
#define PSUM_SZ    (256 * C_ * 64)
#define OFF_PCNT   (OFF_PSUM + PSUM_SZ)
#define WS_NEED_PART ((size_t)(OFF_PCNT + NCHUNK * C_) * 4)

// Kernel 1: streaming per-atom argmin (round-3-proven structure).
// 16 lanes per atom, 8 contiguous floats per lane; codebook rows from L1.
__global__ __launch_bounds__(256) void k_assign(
    const float* __restrict__ h, const int* __restrict__ ei,
    const float* __restrict__ cb, float* __restrict__ hq,
    float* __restrict__ at, float* __restrict__ loss_acc, int N) {
  const int lane16 = threadIdx.x & 15;
  const int gid0 = (blockIdx.x * blockDim.x + threadIdx.x) >> 4;
  const int ngroups = (gridDim.x * blockDim.x) >> 4;
  float loss = 0.f;
  for (int a = gid0; a < N; a += ngroups) {
    const float* hrow = h + (size_t)a * D_ + lane16 * 8;
    float4 h0 = reinterpret_cast<const float4*>(hrow)[0];
    float4 h1 = reinterpret_cast<const float4*>(hrow)[1];
    int e = ei[a];
    const float* cbase = cb + (size_t)e * (K_ * D_);
    float p[4];
#pragma unroll
    for (int j = 0; j < 4; ++j) {
      const float* cr = cbase + j * D_ + lane16 * 8;
      float4 c0 = reinterpret_cast<const float4*>(cr)[0];
      float4 c1 = reinterpret_cast<const float4*>(cr)[1];
      float d0 = h0.x - c0.x, d1 = h0.y - c0.y;
      float d2 = h0.z - c0.z, d3 = h0.w - c0.w;
      float d4 = h1.x - c1.x, d5 = h1.y - c1.y;
      float d6 = h1.z - c1.z, d7 = h1.w - c1.w;
      p[j] = ((d0*d0 + d1*d1) + (d2*d2 + d3*d3)) +
             ((d4*d4 + d5*d5) + (d6*d6 + d7*d7));
    }
#pragma unroll
    for (int s = 1; s < 16; s <<= 1) {
#pragma unroll
      for (int j = 0; j < 4; ++j) p[j] += __shfl_xor(p[j], s, 64);
    }
    float bp = p[0]; int best = 0;
    if (p[1] < bp) { bp = p[1]; best = 1; }
    if (p[2] < bp) { bp = p[2]; best = 2; }
    if (p[3] < bp) { bp = p[3]; best = 3; }
    const float* br = cbase + best * D_ + lane16 * 8;
    float4 b0 = reinterpret_cast<const float4*>(br)[0];
    float4 b1 = reinterpret_cast<const float4*>(br)[1];
    float* orow = hq + (size_t)a * D_ + lane16 * 8;
    reinterpret_cast<float4*>(orow)[0] = b0;
    reinterpret_cast<float4*>(orow)[1] = b1;
    if (lane16 == 0) {
      at[a] = (float)(e * K_ + best);
      loss += bp;
    }
  }
  // block loss reduction via shuffles (no f32 LDS atomics)
  loss += __shfl_xor(loss, 16, 64);
  loss += __shfl_xor(loss, 32, 64);
  __shared__ float wl[4];
  const int w = threadIdx.x >> 6;
  if ((threadIdx.x & 63) == 0) wl[w] = loss;
  __syncthreads();
  if (threadIdx.x == 0)
    atomicAdd(loss_acc, wl[0] + wl[1] + wl[2] + wl[3]);
}

// Kernel 2: streaming segment-sum + counts with NATIVE s32 LDS atomics.
// Block = (chunk, dim-half). LDS acc[400][64] s32 (fixed-point h * 2^16),
// 2-deep prefetch, per-group rotated component order.
__global__ __launch_bounds__(1024) void k_sums3(
    const float* __restrict__ h, const float* __restrict__ at,
    int* __restrict__ psumI, int* __restrict__ pcntI,
    float* __restrict__ sums, float* __restrict__ countsF,
    int dopart, int N) {
  const int half = blockIdx.x & 1;
  const int chunk = blockIdx.x >> 1;
  __shared__ int acc[C_ * 64];
  __shared__ int cnt[C_];
  for (int i = threadIdx.x; i < C_ * 64; i += 1024) acc[i] = 0;
  if (half == 0)
    for (int i = threadIdx.x; i < C_; i += 1024) cnt[i] = 0;
  __syncthreads();

  const int per = (N + NCHUNK - 1) / NCHUNK;    // 2048 (exact)
  const int a0 = chunk * per;
  const int aEnd = min(a0 + per, N);
  const int w = threadIdx.x >> 6;
  const int lane = threadIdx.x & 63;
  const int g = lane >> 4, t = lane & 15;
  const float4* h4 = (const float4*)h;

  int a = a0 + w * 4 + g;
  bool ok0 = a < aEnd, ok1 = (a + 64) < aEnd;
  float4 v0 = {}, v1 = {}; int c0 = 0, c1 = 0;
  if (ok0) { v0 = h4[(size_t)a * 32 + half * 16 + t]; c0 = (int)at[a]; }
  if (ok1) { v1 = h4[(size_t)(a + 64) * 32 + half * 16 + t]; c1 = (int)at[a + 64]; }

  while (ok0) {
    const int an = a + 128;
    const bool okn = an < aEnd;
    float4 vn = {}; int cn = 0;
    if (okn) { vn = h4[(size_t)an * 32 + half * 16 + t]; cn = (int)at[an]; }

    int* ap = &acc[c0 * 64 + t * 4];
    int iv[4] = { __float2int_rn(v0.x * SCALE), __float2int_rn(v0.y * SCALE),
                  __float2int_rn(v0.z * SCALE), __float2int_rn(v0.w * SCALE) };
#pragma unroll
    for (int k = 0; k < 4; ++k) {
      int kk = (k + g) & 3;
      atomicAdd(&ap[kk], iv[kk]);     // native ds_add_u32
    }
    if (half == 0 && t == 0) atomicAdd(&cnt[c0], 1);

    a += 64;
    ok0 = ok1; v0 = v1; c0 = c1;
    ok1 = okn; v1 = vn; c1 = cn;
  }
  __syncthreads();

  if (dopart) {
    int* pb = psumI + (size_t)blockIdx.x * (C_ * 64);
    for (int i = threadIdx.x; i < C_ * 64; i += 1024) pb[i] = acc[i];
    if (half == 0) {
      int* pc = pcntI + (size_t)chunk * C_;
      for (int i = threadIdx.x; i < C_; i += 1024) pc[i] = cnt[i];
    }
  } else {
    for (int i = threadIdx.x; i < C_ * 64; i += 1024) {
      int vv = acc[i];
      if (vv != 0)
        atomicAdd(&sums[(size_t)(i >> 6) * D_ + half * 64 + (i & 63)],
                  (float)vv * INV_SCALE);
    }
    if (half == 0)
      for (int i = threadIdx.x; i < C_; i += 1024)
        if (cnt[i] != 0) atomicAdd(&countsF[i], (float)cnt[i]);
  }
}

// Kernel 3 (partials path): reduce s32 partials -> f32 sums, countsF.
__global__ __launch_bounds__(256) void k_reduce(
    const int* __restrict__ psumI, const int* __restrict__ pcntI,
    float* __restrict__ sums, float* __restrict__ countsF) {
  int idx = blockIdx.x * 256 + threadIdx.x;
  if (idx < C_ * D_) {
    int code = idx >> 7;
    int dim = idx & 127;
    int half = dim >> 6;
    int dl = dim & 63;
    const int* p = psumI + (size_t)half * (C_ * 64) + code * 64 + dl;
    float s = 0.f;
    for (int b = 0; b < NCHUNK; ++b)
      s += (float)p[(size_t)b * 2 * (C_ * 64)];
    sums[idx] = s * INV_SCALE;
  }
  if (idx < C_) {
    int s = 0;
    for (int b = 0; b < NCHUNK; ++b)
      s += pcntI[(size_t)b * C_ + idx];
    countsF[idx] = (float)s;
  }
}

// Kernel 4: EMA finalize + loss scalar.
__global__ __launch_bounds__(256) void k_final(
    const float* __restrict__ cb, const float* __restrict__ ecnt,
    const float* __restrict__ esum, const float* __restrict__ ws,
    float* __restrict__ out, int N) {
  const float* sums = ws;
  const float* countsF = ws + OFF_COUNTS;
  int idx = blockIdx.x * 256 + threadIdx.x;
  const size_t base = (size_t)N * D_ + N + 1;
  if (idx < C_ * D_) {
    int c = idx >> 7;
    int e4 = (c >> 2) << 2;
    bool present = (countsF[e4] + countsF[e4 + 1] + countsF[e4 + 2] + countsF[e4 + 3]) > 0.f;
    float es = esum[idx];
    float s  = sums[idx];
    float ns = present ? 0.99f * es + 0.01f * s : es;
    float ec = ecnt[c];
    float nc = present ? 0.99f * ec + 0.01f * countsF[c] : ec;
    float ncbv = present ? ns / fmaxf(nc, 1e-5f) : cb[idx];
    out[base + idx] = ncbv;
    if ((idx & 127) == 0) out[base + C_ * D_ + c] = nc;
    out[base + C_ * D_ + C_ + idx] = ns;
  }
  if (idx == 0) {
    float loss = ws[OFF_LOSS];
    out[(size_t)N * D_ + N] = 0.25f * loss / ((float)N * (float)D_);
  }
}

extern "C" void kernel_launch(void* const* d_in, const int* in_sizes, int n_in,
                              void* d_out, int out_size, void* d_ws, size_t ws_size,
                              hipStream_t stream) {
  // Identify inputs by size (robust to input-order changes).
  const float* h = nullptr; const int* ei = nullptr;
  const float* cb = nullptr; const float* ecnt = nullptr; const float* esum = nullptr;
  long hsz = -1; int hidx = -1;
  for (int i = 0; i < n_in; ++i)
    if ((long)in_sizes[i] > hsz) { hsz = in_sizes[i]; hidx = i; }
  h = (const float*)d_in[hidx];
  const int N = (int)(hsz / D_);
  for (int i = 0; i < n_in; ++i) {
    if (i == hidx) continue;
    const int s = in_sizes[i];
    if (s == N) ei = (const int*)d_in[i];
    else if (s == C_) ecnt = (const float*)d_in[i];
    else if (s == C_ * D_) { if (!cb) cb = (const float*)d_in[i]; else esum = (const float*)d_in[i]; }
  }

  float* out = (float*)d_out;
  float* hq  = out;
  float* at  = out + (size_t)N * D_;

  float* ws = (float*)d_ws;
  float* sums    = ws;
  float* countsF = ws + OFF_COUNTS;
  float* lossp   = ws + OFF_LOSS;
  int*   psumI   = (int*)(ws + OFF_PSUM);
  int*   pcntI   = (int*)(ws + OFF_PCNT);

  const int dopart = (ws_size >= WS_NEED_PART) ? 1 : 0;

  // zero sums/countsF/loss (~206 KB); psum partials are fully overwritten
  hipMemsetAsync(d_ws, 0, (size_t)(OFF_LOSS + 1) * 4, stream);

  k_assign<<<2048, 256, 0, stream>>>(h, ei, cb, hq, at, lossp, N);
  k_sums3<<<NCHUNK * 2, 1024, 0, stream>>>(h, at, psumI, pcntI,
                                           sums, countsF, dopart, N);
  if (dopart)
    k_reduce<<<(C_ * D_ + 255) / 256, 256, 0, stream>>>(psumI, pcntI, sums, countsF);
  k_final<<<(C_ * D_ + 255) / 256, 256, 0, stream>>>(cb, ecnt, esum, ws, out, N);
}